// Round 4
// baseline (382.460 us; speedup 1.0000x reference)
//
#include <hip/hip_runtime.h>
#include <cstddef>

#define TB 256

constexpr int Bb = 8, Ss = 4096, Dd = 1024, Kk = 64, Hh = 8;
constexpr float INV_TEMP = 10.0f;
constexpr float ATTN_SCALE = 0.08838834764831845f; // 1/sqrt(128)

typedef __attribute__((ext_vector_type(8))) short bf16x8;
typedef __attribute__((ext_vector_type(4))) float f32x4;

#define MFMA(a, b, c) __builtin_amdgcn_mfma_f32_16x16x32_bf16(a, b, c, 0, 0, 0)

// ---------------- workspace layout (bytes) ----------------
constexpr size_t SZ_W1  = (size_t)Kk*Dd*2;        // 128 KB
constexpr size_t SZ_W2  = (size_t)Kk*Kk*2;        // 8 KB
constexpr size_t SZ_WQ  = (size_t)3*Dd*Dd*2;      // 6 MB
constexpr size_t SZ_WD  = (size_t)Dd*Dd*2;        // 2 MB
constexpr size_t SZ_RW  = (size_t)Bb*Ss*Kk*2;     // 4 MB
constexpr size_t SZ_AIF = (size_t)Bb*Kk*Dd*4;     // 2 MB
constexpr size_t SZ_AI2 = (size_t)Bb*Kk*Dd*2;     // 1 MB
constexpr size_t SZ_QK  = (size_t)Bb*Kk*2048*2;   // 2 MB
constexpr size_t SZ_VT  = (size_t)Bb*Dd*Kk*2;     // 1 MB
constexpr size_t SZ_AT  = (size_t)Bb*Kk*Dd*2;     // 1 MB

constexpr size_t OFF_W1H = 0;
constexpr size_t OFF_W1L = OFF_W1H + SZ_W1;
constexpr size_t OFF_W2H = OFF_W1L + SZ_W1;
constexpr size_t OFF_W2L = OFF_W2H + SZ_W2;
constexpr size_t OFF_WQH = OFF_W2L + SZ_W2;
constexpr size_t OFF_WQL = OFF_WQH + SZ_WQ;
constexpr size_t OFF_WOH = OFF_WQL + SZ_WQ;
constexpr size_t OFF_WOL = OFF_WOH + SZ_WD;
constexpr size_t OFF_WPH = OFF_WOL + SZ_WD;
constexpr size_t OFF_WPL = OFF_WPH + SZ_WD;
constexpr size_t OFF_RWH = OFF_WPL + SZ_WD;       // rw natural split [b][s][64]
constexpr size_t OFF_RWL = OFF_RWH + SZ_RW;
constexpr size_t OFF_AIF = OFF_RWL + SZ_RW;       // ai fp32 (atomics target)
constexpr size_t OFF_AIH = OFF_AIF + SZ_AIF;
constexpr size_t OFF_AIL = OFF_AIH + SZ_AI2;
constexpr size_t OFF_U   = OFF_AIL + SZ_AI2;      // union region
// union phase 1 (route->anchor): rwT split [b][64k][4096s]
constexpr size_t OFF_RTH = OFF_U;
constexpr size_t OFF_RTL = OFF_U + SZ_RW;
// union phase 2 (post-anchor): anchor-space tensors
constexpr size_t OFF_QKH = OFF_U;
constexpr size_t OFF_QKL = OFF_QKH + SZ_QK;
constexpr size_t OFF_VTH = OFF_QKL + SZ_QK;
constexpr size_t OFF_VTL = OFF_VTH + SZ_VT;
constexpr size_t OFF_ATH = OFF_VTL + SZ_VT;
constexpr size_t OFF_ATL = OFF_ATH + SZ_AT;
constexpr size_t OFF_AOH = OFF_ATL + SZ_AT;
constexpr size_t OFF_AOL = OFF_AOH + SZ_AT;
constexpr size_t OFF_APH = OFF_AOL + SZ_AT;
constexpr size_t OFF_APL = OFF_APH + SZ_AT;
// total ~= 44.5 MB

// ---------------- scalar helpers ----------------
__device__ inline ushort f2bf(float f) {
    union { float f; uint u; } v; v.f = f;
    return (ushort)((v.u + 0x7fffu + ((v.u >> 16) & 1u)) >> 16);
}
__device__ inline float bf2f(ushort h) {
    union { uint u; float f; } v; v.u = ((uint)h) << 16;
    return v.f;
}
__device__ inline void split2(float f, ushort& h, ushort& l) {
    h = f2bf(f);
    l = f2bf(f - bf2f(h));
}
__device__ inline f32x4 mm3(bf16x8 ah, bf16x8 al, bf16x8 bh, bf16x8 bl, f32x4 c) {
    c = MFMA(ah, bh, c);
    c = MFMA(ah, bl, c);
    c = MFMA(al, bh, c);
    return c;
}

// ---- swizzled LDS bf16 tile, logical [row][64] (stride 72 ushorts = 144B) ---
__device__ inline void st4(ushort* t, int row, int s0, ushort4 v) {
    char* p = (char*)t + row * 144 + ((((s0 >> 3) ^ ((row >> 2) & 7)) << 4) | ((s0 & 7) << 1));
    *(ushort4*)p = v;
}
__device__ inline void st1(ushort* t, int row, int s, ushort v) {
    char* p = (char*)t + row * 144 + ((((s >> 3) ^ ((row >> 2) & 7)) << 4) | ((s & 7) << 1));
    *(ushort*)p = v;
}
__device__ inline bf16x8 ldfrag(const ushort* t, int row, int sblk) {
    const char* p = (const char*)t + row * 144 + (((sblk ^ ((row >> 2) & 7))) << 4);
    return *(const bf16x8*)p;
}
__device__ inline void natf(ushort* thi, ushort* tlo, int row, int s0, float4 v) {
    ushort h0,h1,h2,h3,l0,l1,l2,l3;
    split2(v.x,h0,l0); split2(v.y,h1,l1); split2(v.z,h2,l2); split2(v.w,h3,l3);
    st4(thi, row, s0, make_ushort4(h0,h1,h2,h3));
    st4(tlo, row, s0, make_ushort4(l0,l1,l2,l3));
}
__device__ inline void trf(ushort* thi, ushort* tlo, int rowbase, int s0,
                           float4 a, float4 b, float4 c, float4 d) {
    float m[4][4] = {{a.x,b.x,c.x,d.x},{a.y,b.y,c.y,d.y},
                     {a.z,b.z,c.z,d.z},{a.w,b.w,c.w,d.w}};
#pragma unroll
    for (int i = 0; i < 4; ++i) {
        ushort h[4], l[4];
#pragma unroll
        for (int j = 0; j < 4; ++j) split2(m[i][j], h[j], l[j]);
        st4(thi, rowbase + i, s0, make_ushort4(h[0],h[1],h[2],h[3]));
        st4(tlo, rowbase + i, s0, make_ushort4(l[0],l[1],l[2],l[3]));
    }
}

__global__ __launch_bounds__(TB) void k_zero(float* __restrict__ p, int n4) {
    int i = blockIdx.x * TB + threadIdx.x;
    if (i < n4) ((float4*)p)[i] = make_float4(0.f, 0.f, 0.f, 0.f);
}

// ---------------------------------------------------------------------------
// k_prep: weight transpose+split -> bf16 hi/lo [out][in]
// ---------------------------------------------------------------------------
__global__ __launch_bounds__(TB) void k_prep(
    const float* __restrict__ w1, const float* __restrict__ w2,
    const float* __restrict__ wq, const float* __restrict__ wo,
    const float* __restrict__ wp,
    ushort* __restrict__ w1h, ushort* __restrict__ w1l,
    ushort* __restrict__ w2h, ushort* __restrict__ w2l,
    ushort* __restrict__ wqh, ushort* __restrict__ wql,
    ushort* __restrict__ woh, ushort* __restrict__ wol,
    ushort* __restrict__ wph, ushort* __restrict__ wpl)
{
    __shared__ float t[64][64];
    const int blk = blockIdx.x, tid = threadIdx.x;
    const float* in; ushort* oh; ushort* ol; int R, IC, r0, c0;
    if (blk < 16)        { in = w1; oh = w1h; ol = w1l; R = 1024; IC = 64;
                           r0 = blk * 64; c0 = 0; }
    else if (blk == 16)  { in = w2; oh = w2h; ol = w2l; R = 64;   IC = 64;
                           r0 = 0; c0 = 0; }
    else if (blk < 785)  { int i = blk - 17; in = wq; oh = wqh; ol = wql;
                           R = 1024; IC = 3072; r0 = (i / 48) * 64; c0 = (i % 48) * 64; }
    else if (blk < 1041) { int i = blk - 785; in = wo; oh = woh; ol = wol;
                           R = 1024; IC = 1024; r0 = (i / 16) * 64; c0 = (i % 16) * 64; }
    else                 { int i = blk - 1041; in = wp; oh = wph; ol = wpl;
                           R = 1024; IC = 1024; r0 = (i / 16) * 64; c0 = (i % 16) * 64; }
    {
        int r = tid >> 2, cq = (tid & 3) * 16;
        const float* ip = &in[(size_t)(r0 + r) * IC + c0 + cq];
#pragma unroll
        for (int q = 0; q < 4; ++q)
            *(float4*)&t[r][cq + q * 4] = *(const float4*)(ip + q * 4);
    }
    __syncthreads();
    {
        int oc = tid & 63, or0 = (tid >> 6) * 16;
        ushort th[16], tl[16];
#pragma unroll
        for (int i = 0; i < 16; ++i) split2(t[or0 + i][oc], th[i], tl[i]);
        size_t base = (size_t)(c0 + oc) * R + r0 + or0;
#pragma unroll
        for (int q = 0; q < 4; ++q) {
            *(ushort4*)&oh[base + q * 4] = make_ushort4(th[q*4], th[q*4+1], th[q*4+2], th[q*4+3]);
            *(ushort4*)&ol[base + q * 4] = make_ushort4(tl[q*4], tl[q*4+1], tl[q*4+2], tl[q*4+3]);
        }
    }
}

// ---------------------------------------------------------------------------
// k_route: fused routing. LDS-staged x, reg-direct pre-split weights.
// Outputs rw natural-split AND rw transposed-split.
// grid = 8b * 64 stiles (64 tok) = 512, 256 threads
// ---------------------------------------------------------------------------
__global__ __launch_bounds__(TB) void k_route(
    const float* __restrict__ x, const float* __restrict__ efas,
    const float* __restrict__ w_e, const float* __restrict__ b_e,
    const float* __restrict__ b1, const float* __restrict__ b2,
    const ushort* __restrict__ w1h, const ushort* __restrict__ w1l,
    const ushort* __restrict__ w2h, const ushort* __restrict__ w2l,
    ushort* __restrict__ rwh, ushort* __restrict__ rwl,
    ushort* __restrict__ rth, ushort* __restrict__ rtl)
{
    __shared__ __align__(16) ushort xh[64*72], xl[64*72];  // x chunk / h
    const int tid = threadIdx.x, lane = tid & 63, wv = tid >> 6;
    const int r15 = lane & 15, gg = lane >> 4;
    const int b = blockIdx.x & 7, t0 = (blockIdx.x >> 3) * 64;

    f32x4 acc[4];
#pragma unroll
    for (int nt = 0; nt < 4; ++nt) acc[nt] = (f32x4)0.f;

    for (int kc = 0; kc < 16; ++kc) {
#pragma unroll
        for (int p = 0; p < 4; ++p) {
            int q = tid + p * TB;
            int row = q >> 4, s0 = (q & 15) << 2;
            float4 v = *(const float4*)&x[((size_t)b*Ss + t0 + row)*Dd + kc*64 + s0];
            natf(xh, xl, row, s0, v);
        }
        __syncthreads();
#pragma unroll
        for (int ks = 0; ks < 2; ++ks) {
            bf16x8 ah = ldfrag(xh, wv*16 + r15, ks*4 + gg);
            bf16x8 al = ldfrag(xl, wv*16 + r15, ks*4 + gg);
#pragma unroll
            for (int nt = 0; nt < 4; ++nt) {
                size_t wi = (size_t)(nt*16 + r15)*Dd + kc*64 + ks*32 + gg*8;
                acc[nt] = mm3(ah, al, *(const bf16x8*)&w1h[wi],
                              *(const bf16x8*)&w1l[wi], acc[nt]);
            }
        }
        __syncthreads();
    }
    // h = relu(acc+b1) -> xh/xl (each wave writes only its own 16-row block)
#pragma unroll
    for (int nt = 0; nt < 4; ++nt) {
        float b1v = b1[nt*16 + r15];
#pragma unroll
        for (int j = 0; j < 4; ++j) {
            float hv = fmaxf(acc[nt][j] + b1v, 0.f);
            ushort hh, hl; split2(hv, hh, hl);
            st1(xh, wv*16 + gg*4 + j, nt*16 + r15, hh);
            st1(xl, wv*16 + gg*4 + j, nt*16 + r15, hl);
        }
    }
    __syncthreads();
    // h @ w2
    f32x4 a2[4];
#pragma unroll
    for (int nt = 0; nt < 4; ++nt) a2[nt] = (f32x4)0.f;
#pragma unroll
    for (int ks = 0; ks < 2; ++ks) {
        bf16x8 ah = ldfrag(xh, wv*16 + r15, ks*4 + gg);
        bf16x8 al = ldfrag(xl, wv*16 + r15, ks*4 + gg);
#pragma unroll
        for (int nt = 0; nt < 4; ++nt) {
            size_t wi = (size_t)(nt*16 + r15)*Kk + ks*32 + gg*8;
            a2[nt] = mm3(ah, al, *(const bf16x8*)&w2h[wi],
                         *(const bf16x8*)&w2l[wi], a2[nt]);
        }
    }
    // energies + softmax
    float wev[4], bev[4], b2v[4];
#pragma unroll
    for (int nt = 0; nt < 4; ++nt) {
        wev[nt] = w_e[nt*16 + r15]; bev[nt] = b_e[nt*16 + r15]; b2v[nt] = b2[nt*16 + r15];
    }
    float pr[4][4];
#pragma unroll
    for (int j = 0; j < 4; ++j) {
        int row = t0 + wv*16 + gg*4 + j;
        float ef = efas[(size_t)b*Ss + row];
        float t[4];
#pragma unroll
        for (int nt = 0; nt < 4; ++nt)
            t[nt] = (a2[nt][j] + b2v[nt] + 2.f*(ef*wev[nt] + bev[nt])) * INV_TEMP;
        float m = fmaxf(fmaxf(t[0], t[1]), fmaxf(t[2], t[3]));
#pragma unroll
        for (int off = 1; off <= 8; off <<= 1) m = fmaxf(m, __shfl_xor(m, off));
        float s = 0.f;
#pragma unroll
        for (int nt = 0; nt < 4; ++nt) { t[nt] = __expf(t[nt] - m); s += t[nt]; }
#pragma unroll
        for (int off = 1; off <= 8; off <<= 1) s += __shfl_xor(s, off);
        float inv = 1.f / s;
#pragma unroll
        for (int nt = 0; nt < 4; ++nt) pr[j][nt] = t[nt] * inv;
    }
    // natural split write
#pragma unroll
    for (int j = 0; j < 4; ++j) {
        int row = t0 + wv*16 + gg*4 + j;
#pragma unroll
        for (int nt = 0; nt < 4; ++nt) {
            ushort hh, hl; split2(pr[j][nt], hh, hl);
            size_t o = ((size_t)b*Ss + row)*Kk + nt*16 + r15;
            rwh[o] = hh; rwl[o] = hl;
        }
    }
    // transposed split write (rwT[b][k][s]); 4 tokens contiguous -> ushort4
#pragma unroll
    for (int nt = 0; nt < 4; ++nt) {
        ushort4 vh, vl;
        ushort h0,h1,h2,h3,l0,l1,l2,l3;
        split2(pr[0][nt],h0,l0); split2(pr[1][nt],h1,l1);
        split2(pr[2][nt],h2,l2); split2(pr[3][nt],h3,l3);
        vh = make_ushort4(h0,h1,h2,h3); vl = make_ushort4(l0,l1,l2,l3);
        size_t o = ((size_t)b*Kk + nt*16 + r15)*Ss + t0 + wv*16 + gg*4;
        *(ushort4*)&rth[o] = vh;
        *(ushort4*)&rtl[o] = vl;
    }
}

// ---------------------------------------------------------------------------
// k_anchor: ai[b,k,d] += sum_s rw[s,k]*x[s,d]
// A = rwT reg-direct, B = xT split via LDS. grid = 8b * 8dt(128d) * 8sc = 512
// ---------------------------------------------------------------------------
__global__ __launch_bounds__(TB) void k_anchor(
    const float* __restrict__ x, const ushort* __restrict__ rth,
    const ushort* __restrict__ rtl, float* __restrict__ ai)
{
    __shared__ __align__(16) ushort bh_t[128*72], bl_t[128*72]; // xT [128 d][64 s]
    const int tid = threadIdx.x, lane = tid & 63, wv = tid >> 6;
    const int r15 = lane & 15, gg = lane >> 4;
    const int b = blockIdx.x & 7, dt = (blockIdx.x >> 3) & 7, sc = blockIdx.x >> 6;

    f32x4 acc[4][2];
#pragma unroll
    for (int mt = 0; mt < 4; ++mt)
#pragma unroll
      for (int nl = 0; nl < 2; ++nl) acc[mt][nl] = (f32x4)0.f;

    for (int cc = 0; cc < 8; ++cc) {
        const int sb = sc*512 + cc*64;
#pragma unroll
        for (int p = 0; p < 2; ++p) {    // xT transposed split fill
            int q = tid + p * TB;
            int d0 = (q & 31) << 2, s0 = (q >> 5) << 2;
            const float* base = &x[((size_t)b*Ss + sb + s0)*Dd + dt*128 + d0];
            trf(bh_t, bl_t, d0, s0, *(const float4*)base, *(const float4*)(base + Dd),
                *(const float4*)(base + 2*Dd), *(const float4*)(base + 3*Dd));
        }
        __syncthreads();
#pragma unroll
        for (int ks = 0; ks < 2; ++ks) {
            bf16x8 ah[4], al[4];
#pragma unroll
            for (int mt = 0; mt < 4; ++mt) {
                size_t ri = ((size_t)b*Kk + mt*16 + r15)*Ss + sb + ks*32 + gg*8;
                ah[mt] = *(const bf16x8*)&rth[ri];
                al[mt] = *(const bf16x8*)&rtl[ri];
            }
#pragma unroll
            for (int nl = 0; nl < 2; ++nl) {
                bf16x8 xbh = ldfrag(bh_t, wv*32 + nl*16 + r15, ks*4 + gg);
                bf16x8 xbl = ldfrag(bl_t, wv*32 + nl*16 + r15, ks*4 + gg);
#pragma unroll
                for (int mt = 0; mt < 4; ++mt)
                    acc[mt][nl] = mm3(ah[mt], al[mt], xbh, xbl, acc[mt][nl]);
            }
        }
        __syncthreads();
    }
#pragma unroll
    for (int mt = 0; mt < 4; ++mt)
#pragma unroll
      for (int nl = 0; nl < 2; ++nl)
#pragma unroll
        for (int j = 0; j < 4; ++j) {
            int k = mt*16 + gg*4 + j;
            int d = dt*128 + wv*32 + nl*16 + r15;
            atomicAdd(&ai[((size_t)b*Kk + k)*Dd + d], acc[mt][nl][j]);
        }
}

// ---------------------------------------------------------------------------
// k_cvt: ai fp32 -> split bf16 natural
// ---------------------------------------------------------------------------
__global__ __launch_bounds__(TB) void k_cvt(
    const float* __restrict__ ai, ushort* __restrict__ aih, ushort* __restrict__ ail)
{
    size_t i = ((size_t)blockIdx.x * TB + threadIdx.x) * 4;
    float4 v = *(const float4*)&ai[i];
    ushort h0,h1,h2,h3,l0,l1,l2,l3;
    split2(v.x,h0,l0); split2(v.y,h1,l1); split2(v.z,h2,l2); split2(v.w,h3,l3);
    *(ushort4*)&aih[i] = make_ushort4(h0,h1,h2,h3);
    *(ushort4*)&ail[i] = make_ushort4(l0,l1,l2,l3);
}

// ---------------------------------------------------------------------------
// k_gemm: C[b,64,NDIM] = A-split[b,64,1024] @ WT-split (+bias); reg-direct.
// EPI 0: natural-split out (stride 1024). EPI 1 (qkv): n<2048 natural (stride
// 2048) -> QK buffers; n>=2048 transposed -> VT. EPI 2: transposed out, no bias.
// grid = 8 * NDIM/128
// ---------------------------------------------------------------------------
template <int NDIM, int EPI>
__global__ __launch_bounds__(TB) void k_gemm(
    const ushort* __restrict__ AH, const ushort* __restrict__ AL,
    const ushort* __restrict__ WH, const ushort* __restrict__ WL,
    const float* __restrict__ bias,
    ushort* __restrict__ OH, ushort* __restrict__ OL,
    ushort* __restrict__ TH, ushort* __restrict__ TL)
{
    const int tid = threadIdx.x, lane = tid & 63, wv = tid >> 6;
    const int r15 = lane & 15, gg = lane >> 4;
    constexpr int NT = NDIM / 128;
    const int b = blockIdx.x / NT, n0 = (blockIdx.x % NT) * 128;

    f32x4 acc[4][2];
#pragma unroll
    for (int mt = 0; mt < 4; ++mt)
#pragma unroll
      for (int nl = 0; nl < 2; ++nl) acc[mt][nl] = (f32x4)0.f;

    for (int kc = 0; kc < 32; ++kc) {
        const int kb = kc * 32 + gg * 8;
        bf16x8 ah[4], al[4];
#pragma unroll
        for (int mt = 0; mt < 4; ++mt) {
            size_t aidx = ((size_t)b*64 + mt*16 + r15)*Dd + kb;
            ah[mt] = *(const bf16x8*)&AH[aidx];
            al[mt] = *(const bf16x8*)&AL[aidx];
        }
#pragma unroll
        for (int nl = 0; nl < 2; ++nl) {
            size_t widx = ((size_t)(n0 + wv*32 + nl*16 + r15))*Dd + kb;
            bf16x8 bh = *(const bf16x8*)&WH[widx];
            bf16x8 bl = *(const bf16x8*)&WL[widx];
#pragma unroll
            for (int mt = 0; mt < 4; ++mt)
                acc[mt][nl] = mm3(ah[mt], al[mt], bh, bl, acc[mt][nl]);
        }
    }
#pragma unroll
    for (int nl = 0; nl < 2; ++nl) {
        const int n = n0 + wv*32 + nl*16 + r15;
        float bb = (EPI == 2) ? 0.f : bias[n];
#pragma unroll
        for (int mt = 0; mt < 4; ++mt) {
            if (EPI == 2 || (EPI == 1 && n0 >= 2048)) {
                ushort h[4], l[4];
#pragma unroll
                for (int j = 0; j < 4; ++j) split2(acc[mt][nl][j] + bb, h[j], l[j]);
                int nn = (EPI == 1) ? n - 2048 : n;
                size_t o = ((size_t)b*Dd + nn)*64 + mt*16 + gg*4;
                *(ushort4*)&TH[o] = make_ushort4(h[0],h[1],h[2],h[3]);
                *(ushort4*)&TL[o] = make_ushort4(l[0],l[1],l[2],l[3]);
            } else {
                constexpr int OST = (EPI == 1) ? 2048 : 1024;
#pragma unroll
                for (int j = 0; j < 4; ++j) {
                    ushort hh, hl; split2(acc[mt][nl][j] + bb, hh, hl);
                    size_t o = ((size_t)b*64 + mt*16 + gg*4 + j)*OST + n;
                    OH[o] = hh; OL[o] = hl;
                }
            }
        }
    }
}

// ---------------------------------------------------------------------------
// k_attn: per (b,h): scores (reg-direct Q,K), softmax, PV (reg-direct VT)
// grid = 64
// ---------------------------------------------------------------------------
__global__ __launch_bounds__(TB) void k_attn(
    const ushort* __restrict__ qkh, const ushort* __restrict__ qkl,
    const ushort* __restrict__ vth, const ushort* __restrict__ vtl,
    ushort* __restrict__ atth, ushort* __restrict__ attl)
{
    __shared__ __align__(16) ushort ph[64*72], pl[64*72];
    const int tid = threadIdx.x, lane = tid & 63, wv = tid >> 6;
    const int r15 = lane & 15, gg = lane >> 4;
    const int b = blockIdx.x >> 3, h = blockIdx.x & 7;

    f32x4 sc[4];
#pragma unroll
    for (int nt = 0; nt < 4; ++nt) sc[nt] = (f32x4)0.f;
#pragma unroll
    for (int kb = 0; kb < 4; ++kb) {
        size_t qi = ((size_t)b*64 + wv*16 + r15)*2048 + h*128 + kb*32 + gg*8;
        bf16x8 ah = *(const bf16x8*)&qkh[qi];
        bf16x8 al = *(const bf16x8*)&qkl[qi];
#pragma unroll
        for (int nt = 0; nt < 4; ++nt) {
            size_t ki = ((size_t)b*64 + nt*16 + r15)*2048 + 1024 + h*128 + kb*32 + gg*8;
            sc[nt] = mm3(ah, al, *(const bf16x8*)&qkh[ki],
                         *(const bf16x8*)&qkl[ki], sc[nt]);
        }
    }
    float pr[4][4];
#pragma unroll
    for (int j = 0; j < 4; ++j) {
        float t[4];
#pragma unroll
        for (int nt = 0; nt < 4; ++nt) t[nt] = sc[nt][j] * ATTN_SCALE;
        float m = fmaxf(fmaxf(t[0],t[1]), fmaxf(t[2],t[3]));
#pragma unroll
        for (int off = 1; off <= 8; off <<= 1) m = fmaxf(m, __shfl_xor(m, off));
        float s = 0.f;
#pragma unroll
        for (int nt = 0; nt < 4; ++nt) { t[nt] = __expf(t[nt] - m); s += t[nt]; }
#pragma unroll
        for (int off = 1; off <= 8; off <<= 1) s += __shfl_xor(s, off);
        float inv = 1.f / s;
#pragma unroll
        for (int nt = 0; nt < 4; ++nt) pr[j][nt] = t[nt] * inv;
    }
#pragma unroll
    for (int j = 0; j < 4; ++j)
#pragma unroll
      for (int nt = 0; nt < 4; ++nt) {
        ushort hh, hl; split2(pr[j][nt], hh, hl);
        st1(ph, wv*16 + gg*4 + j, nt*16 + r15, hh);
        st1(pl, wv*16 + gg*4 + j, nt*16 + r15, hl);
      }
    __syncthreads();
    f32x4 o[8];
#pragma unroll
    for (int nt = 0; nt < 8; ++nt) o[nt] = (f32x4)0.f;
#pragma unroll
    for (int ks = 0; ks < 2; ++ks) {
        bf16x8 ah = ldfrag(ph, wv*16 + r15, ks*4 + gg);
        bf16x8 al = ldfrag(pl, wv*16 + r15, ks*4 + gg);
#pragma unroll
        for (int nt = 0; nt < 8; ++nt) {
            size_t vi = ((size_t)b*Dd + h*128 + nt*16 + r15)*64 + ks*32 + gg*8;
            o[nt] = mm3(ah, al, *(const bf16x8*)&vth[vi],
                        *(const bf16x8*)&vtl[vi], o[nt]);
        }
    }
#pragma unroll
    for (int nt = 0; nt < 8; ++nt)
#pragma unroll
      for (int j = 0; j < 4; ++j) {
        ushort hh, hl; split2(o[nt][j], hh, hl);
        size_t oo = ((size_t)b*64 + wv*16 + gg*4 + j)*Dd + h*128 + nt*16 + r15;
        atth[oo] = hh; attl[oo] = hl;
      }
}

// ---------------------------------------------------------------------------
// k_scatter: out = rw @ aop + b_p  (reg-direct both sides, LDS-free)
// grid = 8b * 32st(128 tok) * 8dt(128 d) = 2048
// ---------------------------------------------------------------------------
__global__ __launch_bounds__(TB) void k_scatter(
    const ushort* __restrict__ rwh, const ushort* __restrict__ rwl,
    const ushort* __restrict__ aph, const ushort* __restrict__ apl,
    const float* __restrict__ b_p, float* __restrict__ out)
{
    const int tid = threadIdx.x, lane = tid & 63, wv = tid >> 6;
    const int r15 = lane & 15, gg = lane >> 4;
    const int b = blockIdx.x & 7, st = (blockIdx.x >> 3) & 31, dt = blockIdx.x >> 8;
    const int t0 = st * 128;

    f32x4 acc[2][8];
#pragma unroll
    for (int mt = 0; mt < 2; ++mt)
#pragma unroll
      for (int nt = 0; nt < 8; ++nt) acc[mt][nt] = (f32x4)0.f;

#pragma unroll
    for (int ks = 0; ks < 2; ++ks) {
        bf16x8 ah[2], al[2];
#pragma unroll
        for (int mt = 0; mt < 2; ++mt) {
            size_t ri = ((size_t)b*Ss + t0 + wv*32 + mt*16 + r15)*Kk + ks*32 + gg*8;
            ah[mt] = *(const bf16x8*)&rwh[ri];
            al[mt] = *(const bf16x8*)&rwl[ri];
        }
#pragma unroll
        for (int nt = 0; nt < 8; ++nt) {
            size_t bi = ((size_t)b*Dd + dt*128 + nt*16 + r15)*Kk + ks*32 + gg*8;
            bf16x8 bh = *(const bf16x8*)&aph[bi];
            bf16x8 bl = *(const bf16x8*)&apl[bi];
#pragma unroll
            for (int mt = 0; mt < 2; ++mt)
                acc[mt][nt] = mm3(ah[mt], al[mt], bh, bl, acc[mt][nt]);
        }
    }
#pragma unroll
    for (int nt = 0; nt < 8; ++nt) {
        float bp = b_p[dt*128 + nt*16 + r15];
#pragma unroll
        for (int mt = 0; mt < 2; ++mt)
#pragma unroll
          for (int j = 0; j < 4; ++j)
            out[((size_t)b*Ss + t0 + wv*32 + mt*16 + gg*4 + j)*Dd + dt*128 + nt*16 + r15]
                = acc[mt][nt][j] + bp;
    }
}

extern "C" void kernel_launch(void* const* d_in, const int* in_sizes, int n_in,
                              void* d_out, int out_size, void* d_ws, size_t ws_size,
                              hipStream_t stream)
{
    const float* x     = (const float*)d_in[0];
    const float* efas  = (const float*)d_in[1];
    const float* w_e   = (const float*)d_in[2];
    const float* b_e   = (const float*)d_in[3];
    const float* w1    = (const float*)d_in[4];
    const float* b1    = (const float*)d_in[5];
    const float* w2    = (const float*)d_in[6];
    const float* b2    = (const float*)d_in[7];
    const float* w_qkv = (const float*)d_in[8];
    const float* b_qkv = (const float*)d_in[9];
    const float* w_o   = (const float*)d_in[10];
    const float* b_o   = (const float*)d_in[11];
    const float* w_p   = (const float*)d_in[12];
    const float* b_p   = (const float*)d_in[13];
    float* out = (float*)d_out;
    char* ws = (char*)d_ws;

    ushort* w1h = (ushort*)(ws + OFF_W1H); ushort* w1l = (ushort*)(ws + OFF_W1L);
    ushort* w2h = (ushort*)(ws + OFF_W2H); ushort* w2l = (ushort*)(ws + OFF_W2L);
    ushort* wqh = (ushort*)(ws + OFF_WQH); ushort* wql = (ushort*)(ws + OFF_WQL);
    ushort* woh = (ushort*)(ws + OFF_WOH); ushort* wol = (ushort*)(ws + OFF_WOL);
    ushort* wph = (ushort*)(ws + OFF_WPH); ushort* wpl = (ushort*)(ws + OFF_WPL);
    ushort* rwh = (ushort*)(ws + OFF_RWH); ushort* rwl = (ushort*)(ws + OFF_RWL);
    float*  aif = (float*) (ws + OFF_AIF);
    ushort* aih = (ushort*)(ws + OFF_AIH); ushort* ail = (ushort*)(ws + OFF_AIL);
    ushort* rth = (ushort*)(ws + OFF_RTH); ushort* rtl = (ushort*)(ws + OFF_RTL);
    ushort* qkh = (ushort*)(ws + OFF_QKH); ushort* qkl = (ushort*)(ws + OFF_QKL);
    ushort* vth = (ushort*)(ws + OFF_VTH); ushort* vtl = (ushort*)(ws + OFF_VTL);
    ushort* ath = (ushort*)(ws + OFF_ATH); ushort* atl = (ushort*)(ws + OFF_ATL);
    ushort* aoh = (ushort*)(ws + OFF_AOH); ushort* aol = (ushort*)(ws + OFF_AOL);
    ushort* aph = (ushort*)(ws + OFF_APH); ushort* apl = (ushort*)(ws + OFF_APL);

    hipLaunchKernelGGL(k_prep, dim3(1297), dim3(TB), 0, stream,
                       w1, w2, w_qkv, w_o, w_p,
                       w1h, w1l, w2h, w2l, wqh, wql, woh, wol, wph, wpl);
    hipLaunchKernelGGL(k_zero, dim3(512), dim3(TB), 0, stream,
                       aif, (int)(SZ_AIF / 16));
    hipLaunchKernelGGL(k_route, dim3(512), dim3(TB), 0, stream,
                       x, efas, w_e, b_e, b1, b2, w1h, w1l, w2h, w2l,
                       rwh, rwl, rth, rtl);
    hipLaunchKernelGGL(k_anchor, dim3(512), dim3(TB), 0, stream, x, rth, rtl, aif);
    hipLaunchKernelGGL(k_cvt, dim3(512), dim3(TB), 0, stream, aif, aih, ail);
    hipLaunchKernelGGL((k_gemm<3072, 1>), dim3(192), dim3(TB), 0, stream,
                       aih, ail, wqh, wql, b_qkv, qkh, qkl, vth, vtl);
    hipLaunchKernelGGL(k_attn, dim3(64), dim3(TB), 0, stream,
                       qkh, qkl, vth, vtl, ath, atl);
    hipLaunchKernelGGL((k_gemm<1024, 0>), dim3(64), dim3(TB), 0, stream,
                       ath, atl, woh, wol, b_o, aoh, aol,
                       (ushort*)nullptr, (ushort*)nullptr);
    hipLaunchKernelGGL((k_gemm<1024, 2>), dim3(64), dim3(TB), 0, stream,
                       aoh, aol, wph, wpl, (const float*)nullptr,
                       (ushort*)nullptr, (ushort*)nullptr, aph, apl);
    hipLaunchKernelGGL(k_scatter, dim3(2048), dim3(TB), 0, stream,
                       rwh, rwl, aph, apl, b_p, out);
}